// Round 19
// baseline (479.972 us; speedup 1.0000x reference)
//
#include <hip/hip_runtime.h>
#include <hip/hip_bf16.h>

#define DEVINL __device__ __forceinline__

constexpr int N_NODES = 50000;
constexpr int N_EDGES = 800000;
constexpr int F_IN    = 256;
constexpr int H       = 96;
constexpr int NG      = 64;                  // graphs
constexpr float BN_EPS = 1e-5f;
constexpr int SLOT    = 64;                  // fixed col slots per node (max real deg ~45)
constexpr int NREP    = 8;                   // pooled replicas (one per XCD slot)
constexpr int REPSZ   = NG * H + NG;         // floats per pooled replica

typedef short bf16x8 __attribute__((ext_vector_type(8)));
typedef float f32x4  __attribute__((ext_vector_type(4)));

DEVINL float bf2f(unsigned int u) {
    union { unsigned int i; float f; } c; c.i = u << 16; return c.f;
}
DEVINL unsigned short f2bf(float f) {
    union { float f; unsigned int i; } c; c.f = f;
    unsigned int x = c.i;
    return (unsigned short)((x + 0x7fffu + ((x >> 16) & 1u)) >> 16);
}
DEVINL float lrelu01(float v) { return v >= 0.f ? v : 0.01f * v; }
// dtype-flag aware scalar load of a "float tensor" input
DEVINL float ldf(const void* p, size_t i, int f32) {
    return f32 ? ((const float*)p)[i] : bf2f(((const unsigned short*)p)[i]);
}

// ---------------------------------------------------------------------------
// dtype detect (block 0) + zero the CSR fill array (all blocks).
// ---------------------------------------------------------------------------
__global__ __launch_bounds__(256) void detect_fill_k(const unsigned short* __restrict__ x,
                                                     int* __restrict__ flag,
                                                     int* __restrict__ fill)
{
    if (blockIdx.x == 0 && threadIdx.x < 64) {
        int l = threadIdx.x;
        float f = bf2f(x[l]);
        bool huge = !(fabsf(f) <= 1e4f);
        unsigned long long m = __ballot(huge);
        if (l == 0) flag[0] = (__popcll(m) >= 8) ? 1 : 0;   // 1 = fp32, 0 = bf16
    }
    int i = blockIdx.x * 256 + threadIdx.x;
    if (i < N_NODES) fill[i] = 0;
}

// ---------------------------------------------------------------------------
// Pack ALL 6 weight matrices into MFMA B-fragment order in one dispatch.
// Blocks 0..95: emb (K=256). Blocks 96..275: 5 x (K=96, 36 each).
// ---------------------------------------------------------------------------
__global__ __launch_bounds__(256) void wpackall_k(
    const void* __restrict__ sE, const void* __restrict__ s0,
    const void* __restrict__ s1, const void* __restrict__ s2,
    const void* __restrict__ s3, const void* __restrict__ s4,
    const int* __restrict__ dflag,
    unsigned short* __restrict__ dE, unsigned short* __restrict__ d0,
    unsigned short* __restrict__ d1, unsigned short* __restrict__ d2,
    unsigned short* __restrict__ d3, unsigned short* __restrict__ d4)
{
    int b = blockIdx.x;
    const void* src; unsigned short* dst; int K, i0;
    if (b < 96) { src = sE; dst = dE; K = F_IN; i0 = b * 256; }
    else {
        int m = (b - 96) / 36, r = (b - 96) % 36;
        K = H; i0 = r * 256;
        if      (m == 0) { src = s0; dst = d0; }
        else if (m == 1) { src = s1; dst = d1; }
        else if (m == 2) { src = s2; dst = d2; }
        else if (m == 3) { src = s3; dst = d3; }
        else             { src = s4; dst = d4; }
    }
    int i = i0 + threadIdx.x;
    if (i >= K * 96) return;
    int c   = i / 3072;
    int rem = i - c * 3072;
    int t    = rem >> 9;
    int rem2 = rem & 511;
    int l = rem2 >> 3, j = rem2 & 7;
    int k = c * 32 + (l >> 4) * 8 + j;
    int n = t * 16 + (l & 15);
    if (dflag[0]) dst[i] = f2bf(((const float*)src)[k * 96 + n]);
    else          dst[i] = ((const unsigned short*)src)[k * 96 + n];
}

// ---------------------------------------------------------------------------
// MFMA GEMM: out[M,96] = A[M,K] @ W[K,96], v_mfma_f32_16x16x32_bf16.
// Wave owns 16 rows x 96 cols (6 tiles, 6x f32x4 acc). No LDS, no barriers.
// EPI: 0 plain, 1 lrelu(acc+bias), 2 lrelu(acc+bias) -> out and out2
// AWS: 1 if A is workspace bf16, 0 if A is an input (dtype per dflag)
// SD : 1 -> also emit s,d per row from the fp32 acc (fused old sd_k)
// ABN: 1 -> A-load applies BN coef + lrelu + residual inline
// SCAT:1 -> blocks >= ngb instead scatter edges [e0,e1) into the 64-slot CSR
//      (hides the latency-bound atomic scatter under the MFMA-bound GEMM)
// ---------------------------------------------------------------------------
template<int EPI, int AWS, int SD, int ABN, int SCAT>
__global__ __launch_bounds__(256) void mgemm_k(
    const void* __restrict__ Ap, const unsigned short* __restrict__ Wpk,
    const void* __restrict__ bp, const int* __restrict__ dflag,
    unsigned short* __restrict__ out, unsigned short* __restrict__ out2,
    const void* __restrict__ as_, const void* __restrict__ ad_,
    float* __restrict__ s, float* __restrict__ d,
    const float* __restrict__ coefp, const unsigned short* __restrict__ idn,
    const int* __restrict__ ei, int* __restrict__ fill,
    unsigned short* __restrict__ colw, int e0, int e1, int ngb,
    int M, int K)
{
    if (SCAT && (int)blockIdx.x >= ngb) {
        int e = e0 + ((int)blockIdx.x - ngb) * 256 + threadIdx.x;
        if (e < e1) {
            int srcv = ei[e];
            int dstv = ei[N_EDGES + e];
            int p = atomicAdd(&fill[dstv], 1);
            if (p < SLOT) colw[(size_t)dstv * SLOT + p] = (unsigned short)srcv;
        }
        return;
    }

    const int f32  = AWS ? 0 : dflag[0];
    const int wf32 = dflag[0];
    const int l    = threadIdx.x & 63;
    const int wave = threadIdx.x >> 6;
    const int row0 = blockIdx.x * 64 + wave * 16;
    const int m    = l & 15;
    const int q    = l >> 4;
    const int arow = row0 + m;
    const bool aok = arow < M;

    f32x4 acc[6] = {};
    const int nch = K >> 5;
    const bf16x8* wp = (const bf16x8*)Wpk;

    for (int c = 0; c < nch; c++) {
        bf16x8 a = {};
        if (aok) {
            if (ABN) {
                const int f0 = c * 32 + q * 8;
                uint4 xu = *(const uint4*)((const unsigned short*)Ap + (size_t)arow * K + f0);
                uint4 iu = *(const uint4*)(idn + (size_t)arow * K + f0);
                unsigned int xs[4] = { xu.x, xu.y, xu.z, xu.w };
                unsigned int is[4] = { iu.x, iu.y, iu.z, iu.w };
                #pragma unroll
                for (int jj = 0; jj < 4; jj++) {
                    int f = f0 + 2 * jj;
                    float v0 = lrelu01(bf2f(xs[jj] & 0xffff) * coefp[f]     + coefp[96 + f])     + bf2f(is[jj] & 0xffff);
                    float v1 = lrelu01(bf2f(xs[jj] >> 16)    * coefp[f + 1] + coefp[96 + f + 1]) + bf2f(is[jj] >> 16);
                    a[2 * jj]     = (short)f2bf(v0);
                    a[2 * jj + 1] = (short)f2bf(v1);
                }
            } else if (f32) {
                const float* A = (const float*)Ap + (size_t)arow * K + c * 32 + q * 8;
                #pragma unroll
                for (int j = 0; j < 8; j++) a[j] = (short)f2bf(A[j]);
            } else {
                a = *(const bf16x8*)((const unsigned short*)Ap + (size_t)arow * K + c * 32 + q * 8);
            }
        }
        const int base = c * 384 + l;
        #pragma unroll
        for (int t = 0; t < 6; t++)
            acc[t] = __builtin_amdgcn_mfma_f32_16x16x32_bf16(a, wp[base + t * 64], acc[t], 0, 0, 0);
    }

    float bv[6];
    if (EPI > 0) {
        #pragma unroll
        for (int t = 0; t < 6; t++) bv[t] = ldf(bp, t * 16 + m, wf32);
    }
    #pragma unroll
    for (int r = 0; r < 4; r++) {
        int rr = row0 + q * 4 + r;
        if (rr >= M) continue;
        size_t o = (size_t)rr * 96 + m;
        #pragma unroll
        for (int t = 0; t < 6; t++) {
            float v = acc[t][r];
            if (EPI > 0) v = lrelu01(v + bv[t]);
            unsigned short sv = f2bf(v);
            out[o + t * 16] = sv;
            if (EPI == 2) out2[o + t * 16] = sv;
        }
    }

    if (SD) {
        float asv[6], adv[6];
        #pragma unroll
        for (int t = 0; t < 6; t++) {
            asv[t] = ldf(as_, t * 16 + m, wf32);
            adv[t] = ldf(ad_, t * 16 + m, wf32);
        }
        #pragma unroll
        for (int r = 0; r < 4; r++) {
            float ps = 0.f, pd = 0.f;
            #pragma unroll
            for (int t = 0; t < 6; t++) {
                ps = fmaf(acc[t][r], asv[t], ps);
                pd = fmaf(acc[t][r], adv[t], pd);
            }
            #pragma unroll
            for (int off = 1; off < 16; off <<= 1) {
                ps += __shfl_xor(ps, off);
                pd += __shfl_xor(pd, off);
            }
            int rr = row0 + q * 4 + r;
            if (m == 0 && rr < M) { s[rr] = ps; d[rr] = pd; }
        }
    }
}

// ---------------------------------------------------------------------------
// GAT aggregation, one wave per destination node (fixed-stride CSR, real
// edges only — the self-loop is implicit). Softmax via shfl; (u,w) staged in
// per-wave LDS; gather 16-edge-batched over padded deg.
// Block 0 zeroes bnsum + ticket; layer 2 blocks also zero the pooled replicas.
// ---------------------------------------------------------------------------
__global__ __launch_bounds__(256) void agg_k(
    const unsigned short* __restrict__ h2, const float* __restrict__ s,
    const float* __restrict__ d, const int* __restrict__ fill,
    const unsigned short* __restrict__ col, const void* __restrict__ bias,
    const int* __restrict__ dflag, unsigned short* __restrict__ out,
    float* __restrict__ bnsum, int* __restrict__ tick,
    float* __restrict__ zp, int M)
{
    __shared__ uint2 uwb[4][80];   // 65 entries max + pad (batches reach 80)
    if (blockIdx.x == 0) {
        if (threadIdx.x < 192) bnsum[threadIdx.x] = 0.f;
        if (threadIdx.x == 192) *tick = 0;
    }
    if (zp) {
        int zi = blockIdx.x * 256 + threadIdx.x;
        if (zi < NREP * REPSZ) zp[zi] = 0.f;
    }
    int f32 = dflag[0];
    int v = (blockIdx.x * blockDim.x + threadIdx.x) >> 6;
    int l = threadIdx.x & 63;
    int wv = threadIdx.x >> 6;
    if (v >= M) return;
    int st   = v * SLOT;
    int degr = min(fill[v], SLOT - 1);   // real edges
    int deg  = degr + 1;                 // + implicit self loop

    float dv = d[v];
    int u = 0; float e = -1e30f;
    if (l < degr) {
        u = col[st + l];
        float t = s[u] + dv;
        e = t >= 0.f ? t : 0.2f * t;
    } else if (l == degr) {
        u = v;
        float t = s[v] + dv;
        e = t >= 0.f ? t : 0.2f * t;
    }
    float lm = e;
    #pragma unroll
    for (int off = 32; off > 0; off >>= 1) lm = fmaxf(lm, __shfl_xor(lm, off));
    float w = (l < deg) ? __expf(e - lm) : 0.f;
    float ls = w;
    #pragma unroll
    for (int off = 32; off > 0; off >>= 1) ls += __shfl_xor(ls, off);
    float rden = 1.0f / ls;

    uwb[wv][l] = make_uint2((unsigned int)u, __float_as_uint(w));
    if (l < 16) uwb[wv][64 + l] = make_uint2(0u, 0u);

    bool hw = (l < 48);
    int  c2 = 2 * l;
    float a0 = 0.f, a1 = 0.f;
    const uint2* myuw = uwb[wv];
    for (int j = 0; j < deg; j += 16) {
        uint2 p[16];
        #pragma unroll
        for (int k = 0; k < 16; k++) p[k] = myuw[j + k];
        if (hw) {
            unsigned int hv[16];
            #pragma unroll
            for (int k = 0; k < 16; k++)
                hv[k] = *(const unsigned int*)(h2 + (size_t)p[k].x * 96 + c2);
            #pragma unroll
            for (int k = 0; k < 16; k++) {
                float wj = __uint_as_float(p[k].y);
                a0 = fmaf(wj, bf2f(hv[k] & 0xffff), a0);
                a1 = fmaf(wj, bf2f(hv[k] >> 16),    a1);
            }
        }
    }
    if (hw) {
        float b0 = ldf(bias, c2,     f32);
        float b1 = ldf(bias, c2 + 1, f32);
        unsigned int o = (unsigned int)f2bf(a0 * rden + b0)
                       | ((unsigned int)f2bf(a1 * rden + b1) << 16);
        *(unsigned int*)(out + (size_t)v * 96 + c2) = o;
    }
}

// ---------------------------------------------------------------------------
// BatchNorm statistics WITH fused coefficient computation: each block
// accumulates into bnsum via atomics, fences, takes a ticket; the LAST block
// reads the totals back coherently (atomicAdd(p, 0.f)) and writes coef.
// Removes the 3 bncoef dispatches + launch gaps.
// ---------------------------------------------------------------------------
__global__ __launch_bounds__(192) void bnstats_k(const unsigned short* __restrict__ x,
                                                 float* __restrict__ sums,
                                                 int* __restrict__ tick,
                                                 const void* __restrict__ g_,
                                                 const void* __restrict__ b_,
                                                 const int* __restrict__ dflag,
                                                 float* __restrict__ coef, int M)
{
    int c  = threadIdx.x % 96;
    int g2 = threadIdx.x / 96;
    float s = 0.f, q = 0.f;
    for (int r = blockIdx.x * 2 + g2; r < M; r += gridDim.x * 2) {
        float v = bf2f(x[(size_t)r * 96 + c]);
        s += v; q += v * v;
    }
    __shared__ float lsd[192], lqd[192];
    __shared__ int lastf;
    lsd[threadIdx.x] = s; lqd[threadIdx.x] = q;
    __syncthreads();
    if (g2 == 0) {
        atomicAdd(&sums[c],      s + lsd[threadIdx.x + 96]);
        atomicAdd(&sums[96 + c], q + lqd[threadIdx.x + 96]);
    }
    __threadfence();
    if (threadIdx.x == 0) {
        int old = atomicAdd(tick, 1);
        lastf = (old == (int)gridDim.x - 1) ? 1 : 0;
    }
    __syncthreads();
    if (lastf && g2 == 0) {
        float su = atomicAdd(&sums[c], 0.f);        // coherent read
        float sq = atomicAdd(&sums[96 + c], 0.f);
        int f32 = dflag[0];
        float mu  = su * (1.f / N_NODES);
        float var = sq * (1.f / N_NODES) - mu * mu;
        float rinv = 1.0f / sqrtf(var + BN_EPS);
        float sc = ldf(g_, c, f32) * rinv;
        coef[c]      = sc;
        coef[96 + c] = ldf(b_, c, f32) - mu * sc;
    }
}

// ---------------------------------------------------------------------------
// Fused tail: BN+lrelu+residual -> Poincare expmap0 -> mean-pool, 16
// nodes/wave with full ILP; 8-replica pooled accumulation (blockIdx&7).
// ---------------------------------------------------------------------------
__global__ __launch_bounds__(256) void bnpool_k(
    const unsigned short* __restrict__ h, const float* __restrict__ coef,
    const unsigned short* __restrict__ iden, const int* __restrict__ batch,
    float* __restrict__ pooled8, int M)
{
    int w = (blockIdx.x * blockDim.x + threadIdx.x) >> 6;
    int l = threadIdx.x & 63;
    int v0 = w * 16;
    if (v0 >= M) return;
    float* P = pooled8 + (blockIdx.x & (NREP - 1)) * REPSZ;
    float* C = P + NG * H;
    bool hw = (l < 48);
    int  c2 = 2 * l;
    float sc0 = 0.f, sc1 = 0.f, sh0 = 0.f, sh1 = 0.f;
    if (hw) {
        sc0 = coef[c2]; sc1 = coef[c2 + 1];
        sh0 = coef[96 + c2]; sh1 = coef[97 + c2];
    }
    int nv = min(16, M - v0);

    int gb[16];
    #pragma unroll
    for (int k = 0; k < 16; k++) gb[k] = batch[v0 + min(k, nv - 1)];

    float x0[16], x1[16], q[16];
    #pragma unroll
    for (int k = 0; k < 16; k++) { x0[k] = 0.f; x1[k] = 0.f; q[k] = 0.f; }
    if (hw) {
        unsigned int xu[16], iu[16];
        #pragma unroll
        for (int k = 0; k < 16; k++) {
            int v = v0 + k;
            if (k < nv) {
                xu[k] = *(const unsigned int*)(h    + (size_t)v * 96 + c2);
                iu[k] = *(const unsigned int*)(iden + (size_t)v * 96 + c2);
            } else { xu[k] = 0u; iu[k] = 0u; }
        }
        #pragma unroll
        for (int k = 0; k < 16; k++) {
            x0[k] = lrelu01(bf2f(xu[k] & 0xffff) * sc0 + sh0) + bf2f(iu[k] & 0xffff);
            x1[k] = lrelu01(bf2f(xu[k] >> 16)    * sc1 + sh1) + bf2f(iu[k] >> 16);
            q[k]  = x0[k] * x0[k] + x1[k] * x1[k];
        }
    }

    #pragma unroll
    for (int off = 32; off > 0; off >>= 1) {
        #pragma unroll
        for (int k = 0; k < 16; k++) q[k] += __shfl_xor(q[k], off);
    }

    float f[16];
    #pragma unroll
    for (int k = 0; k < 16; k++) {
        float n = fmaxf(sqrtf(q[k]), 1e-15f);
        if (n < 15.f) {
            float t = __expf(2.f * n);
            f[k] = (t - 1.f) / ((t + 1.f) * n);
        } else {
            f[k] = 1.f / n;
        }
    }

    float a0 = 0.f, a1 = 0.f, cnt = 0.f;
    int curg = -1;
    for (int k = 0; k < nv; k++) {
        int g = gb[k];
        if (g != curg) {
            if (curg >= 0) {
                if (hw) {
                    atomicAdd(&P[curg * 96 + c2],     a0);
                    atomicAdd(&P[curg * 96 + c2 + 1], a1);
                }
                if (l == 0) atomicAdd(&C[curg], cnt);
            }
            a0 = a1 = 0.f; cnt = 0.f; curg = g;
        }
        a0 = fmaf(f[k], x0[k], a0);
        a1 = fmaf(f[k], x1[k], a1);
        cnt += 1.f;
    }
    if (curg >= 0) {
        if (hw) {
            atomicAdd(&P[curg * 96 + c2],     a0);
            atomicAdd(&P[curg * 96 + c2 + 1], a1);
        }
        if (l == 0) atomicAdd(&C[curg], cnt);
    }
}

// ---------------------------------------------------------------------------
// Head: one block per graph. Sums the 8 pooled replicas, then
// pooled/cnt -> fc3+lrelu -> fc4 -> out.
// ---------------------------------------------------------------------------
__global__ __launch_bounds__(64) void head_k(const float* __restrict__ pooled8,
                                             const void* __restrict__ w3,
                                             const void* __restrict__ b3,
                                             const void* __restrict__ w4,
                                             const void* __restrict__ b4,
                                             const int* __restrict__ dflag,
                                             void* __restrict__ outv)
{
    int g = blockIdx.x;
    int t = threadIdx.x;
    int f32 = dflag[0];
    __shared__ float p[96];
    __shared__ float o[48];
    float cs = 0.f;
    #pragma unroll
    for (int r = 0; r < NREP; r++) cs += pooled8[r * REPSZ + NG * H + g];
    float inv = 1.0f / fmaxf(cs, 1.0f);
    for (int c = t; c < 96; c += 64) {
        float v = 0.f;
        #pragma unroll
        for (int r = 0; r < NREP; r++) v += pooled8[r * REPSZ + g * 96 + c];
        p[c] = v * inv;
    }
    __syncthreads();
    if (t < 48) {
        float a = ldf(b3, t, f32);
        #pragma unroll
        for (int c = 0; c < 96; c++) a = fmaf(p[c], ldf(w3, (size_t)c * 48 + t, f32), a);
        o[t] = lrelu01(a);
    }
    __syncthreads();
    if (t < 4) {
        float a = ldf(b4, t, f32);
        #pragma unroll
        for (int j = 0; j < 48; j++) a = fmaf(o[j], ldf(w4, j * 4 + t, f32), a);
        if (f32) ((float*)outv)[g * 4 + t] = a;
        else     ((unsigned short*)outv)[g * 4 + t] = f2bf(a);
    }
}

// ---------------------------------------------------------------------------
extern "C" void kernel_launch(void* const* d_in, const int* in_sizes, int n_in,
                              void* d_out, int out_size, void* d_ws, size_t ws_size,
                              hipStream_t stream)
{
    const void* x     = d_in[0];
    const int*  ei    = (const int*)d_in[1];
    const int*  batch = (const int*)d_in[2];
    const void* embW  = d_in[3];
    const void* embB  = d_in[4];
    const void* convW[3]  = { d_in[5],  d_in[9],  d_in[13] };
    const void* convAs[3] = { d_in[6],  d_in[10], d_in[14] };
    const void* convAd[3] = { d_in[7],  d_in[11], d_in[15] };
    const void* convB[3]  = { d_in[8],  d_in[12], d_in[16] };
    const void* fcW[2]    = { d_in[17], d_in[19] };
    const void* fcB[2]    = { d_in[18], d_in[20] };
    const void* bnG[3]    = { d_in[21], d_in[23], d_in[25] };
    const void* bnB[3]    = { d_in[22], d_in[24], d_in[26] };
    const void* fc3W = d_in[27];
    const void* fc3b = d_in[28];
    const void* fc4W = d_in[29];
    const void* fc4b = d_in[30];

    // ---- workspace layout (~37 MiB of the 256 MiB d_ws) ----
    char* wp_ = (char*)d_ws;
    auto alloc = [&](size_t b) { char* p = wp_; wp_ += (b + 255) & ~(size_t)255; return p; };
    int*   dflag = (int*)alloc(256);
    unsigned short* ident = (unsigned short*)alloc((size_t)N_NODES * H * 2);
    unsigned short* hA    = (unsigned short*)alloc((size_t)N_NODES * H * 2);
    unsigned short* hB    = (unsigned short*)alloc((size_t)N_NODES * H * 2);
    float* s_sc  = (float*)alloc((size_t)N_NODES * 4);
    float* d_sc  = (float*)alloc((size_t)N_NODES * 4);
    float* bnsum = (float*)alloc(192 * 4);
    int*   tick  = (int*)alloc(256);
    float* coef  = (float*)alloc(192 * 4);
    float* pooled8 = (float*)alloc((size_t)NREP * REPSZ * 4);
    int*   fill  = (int*)alloc((size_t)N_NODES * 4);
    unsigned short* col = (unsigned short*)alloc((size_t)N_NODES * SLOT * 2);
    // packed MFMA B-fragment weights: emb (256x96) + 5 x (96x96)
    unsigned short* wpkEmb = (unsigned short*)alloc((size_t)F_IN * 96 * 2);
    unsigned short* wpkS[5];
    for (int i = 0; i < 5; i++) wpkS[i] = (unsigned short*)alloc((size_t)H * 96 * 2);

    const int GM = (N_NODES + 63) / 64;          // gemm grid (64 rows/block)
    const int GW = (N_NODES * 64 + 255) / 256;   // wave-per-node grid
    const int GP = ((N_NODES + 15) / 16 * 64 + 255) / 256;  // bnpool grid (16 nodes/wave)
    const int GF = (N_NODES + 255) / 256;        // detect+fill grid
    const int EH = N_EDGES / 2;                  // edge half-point
    const int GS = (EH + 255) / 256;             // scatter blocks per half

    // ---- dtype detect + fill zero (fused) ----
    detect_fill_k<<<GF, 256, 0, stream>>>((const unsigned short*)x, dflag, fill);

    // ---- pack all weights into MFMA fragment order (1 dispatch) ----
    wpackall_k<<<276, 256, 0, stream>>>(embW, convW[0], convW[1], convW[2], fcW[0], fcW[1],
                                        dflag, wpkEmb, wpkS[0], wpkS[1], wpkS[2], wpkS[3], wpkS[4]);

    // ---- embed (+ scatter of edges [0, EH) riding along) ----
    mgemm_k<2, 0, 0, 0, 1><<<GM + GS, 256, 0, stream>>>(
        x, wpkEmb, embB, dflag, hA, ident,
        nullptr, nullptr, nullptr, nullptr, nullptr, nullptr,
        ei, fill, col, 0, EH, GM, N_NODES, F_IN);

    unsigned short* hcur = hA;
    unsigned short* htmp = hB;

    for (int l = 0; l < 3; l++) {
        // h2 = h @ convW, fused s,d; conv0 also carries scatter half 2
        if (l == 0) {
            mgemm_k<0, 1, 1, 0, 1><<<GM + GS, 256, 0, stream>>>(
                hcur, wpkS[0], nullptr, dflag, htmp, nullptr,
                convAs[0], convAd[0], s_sc, d_sc, nullptr, nullptr,
                ei, fill, col, EH, N_EDGES, GM, N_NODES, H);
        } else {
            mgemm_k<0, 1, 1, 0, 0><<<GM, 256, 0, stream>>>(
                hcur, wpkS[l], nullptr, dflag, htmp, nullptr,
                convAs[l], convAd[l], s_sc, d_sc, nullptr, nullptr,
                nullptr, nullptr, nullptr, 0, 0, GM, N_NODES, H);
        }
        // aggregation (zeroes bnsum+tick; layer 2 also zeroes pooled replicas)
        agg_k<<<GW, 256, 0, stream>>>(htmp, s_sc, d_sc, fill, col, convB[l], dflag, hcur,
                                      bnsum, tick, (l == 2) ? pooled8 : nullptr, N_NODES);
        // BN stats with fused coef computation (last-block ticket)
        bnstats_k<<<512, 192, 0, stream>>>(hcur, bnsum, tick, bnG[l], bnB[l], dflag, coef, N_NODES);
        if (l < 2) {
            // fc gemm with BN+lrelu+residual fused into the A-load
            mgemm_k<1, 1, 0, 1, 0><<<GM, 256, 0, stream>>>(
                hcur, wpkS[3 + l], fcB[l], dflag, htmp, nullptr,
                nullptr, nullptr, nullptr, nullptr, coef, ident,
                nullptr, nullptr, nullptr, 0, 0, GM, N_NODES, H);
            unsigned short* t = hcur; hcur = htmp; htmp = t;
        }
    }

    // ---- fused BN+Poincare+pool (8-replica) + head ----
    bnpool_k<<<GP, 256, 0, stream>>>(hcur, coef, ident, batch, pooled8, N_NODES);
    head_k<<<NG, 64, 0, stream>>>(pooled8, fc3W, fc3b, fc4W, fc4b, dflag, d_out);
}

// Round 20
// 436.270 us; speedup vs baseline: 1.1002x; 1.1002x over previous
//
#include <hip/hip_runtime.h>
#include <hip/hip_bf16.h>

#define DEVINL __device__ __forceinline__

constexpr int N_NODES = 50000;
constexpr int N_EDGES = 800000;
constexpr int F_IN    = 256;
constexpr int H       = 96;
constexpr int NG      = 64;                  // graphs
constexpr float BN_EPS = 1e-5f;
constexpr int SLOT    = 64;                  // fixed col slots per node (max real deg ~45)
constexpr int NREP    = 8;                   // pooled replicas (one per XCD slot)
constexpr int REPSZ   = NG * H + NG;         // floats per pooled replica

typedef short bf16x8 __attribute__((ext_vector_type(8)));
typedef float f32x4  __attribute__((ext_vector_type(4)));

DEVINL float bf2f(unsigned int u) {
    union { unsigned int i; float f; } c; c.i = u << 16; return c.f;
}
DEVINL unsigned short f2bf(float f) {
    union { float f; unsigned int i; } c; c.f = f;
    unsigned int x = c.i;
    return (unsigned short)((x + 0x7fffu + ((x >> 16) & 1u)) >> 16);
}
DEVINL float lrelu01(float v) { return v >= 0.f ? v : 0.01f * v; }
// dtype-flag aware scalar load of a "float tensor" input
DEVINL float ldf(const void* p, size_t i, int f32) {
    return f32 ? ((const float*)p)[i] : bf2f(((const unsigned short*)p)[i]);
}

// ---------------------------------------------------------------------------
// dtype detect (block 0) + zero the CSR fill array (all blocks).
// ---------------------------------------------------------------------------
__global__ __launch_bounds__(256) void detect_fill_k(const unsigned short* __restrict__ x,
                                                     int* __restrict__ flag,
                                                     int* __restrict__ fill)
{
    if (blockIdx.x == 0 && threadIdx.x < 64) {
        int l = threadIdx.x;
        float f = bf2f(x[l]);
        bool huge = !(fabsf(f) <= 1e4f);
        unsigned long long m = __ballot(huge);
        if (l == 0) flag[0] = (__popcll(m) >= 8) ? 1 : 0;   // 1 = fp32, 0 = bf16
    }
    int i = blockIdx.x * 256 + threadIdx.x;
    if (i < N_NODES) fill[i] = 0;
}

// ---------------------------------------------------------------------------
// Pack ALL 6 weight matrices into MFMA B-fragment order in one dispatch.
// Blocks 0..95: emb (K=256). Blocks 96..275: 5 x (K=96, 36 each).
// ---------------------------------------------------------------------------
__global__ __launch_bounds__(256) void wpackall_k(
    const void* __restrict__ sE, const void* __restrict__ s0,
    const void* __restrict__ s1, const void* __restrict__ s2,
    const void* __restrict__ s3, const void* __restrict__ s4,
    const int* __restrict__ dflag,
    unsigned short* __restrict__ dE, unsigned short* __restrict__ d0,
    unsigned short* __restrict__ d1, unsigned short* __restrict__ d2,
    unsigned short* __restrict__ d3, unsigned short* __restrict__ d4)
{
    int b = blockIdx.x;
    const void* src; unsigned short* dst; int K, i0;
    if (b < 96) { src = sE; dst = dE; K = F_IN; i0 = b * 256; }
    else {
        int m = (b - 96) / 36, r = (b - 96) % 36;
        K = H; i0 = r * 256;
        if      (m == 0) { src = s0; dst = d0; }
        else if (m == 1) { src = s1; dst = d1; }
        else if (m == 2) { src = s2; dst = d2; }
        else if (m == 3) { src = s3; dst = d3; }
        else             { src = s4; dst = d4; }
    }
    int i = i0 + threadIdx.x;
    if (i >= K * 96) return;
    int c   = i / 3072;
    int rem = i - c * 3072;
    int t    = rem >> 9;
    int rem2 = rem & 511;
    int l = rem2 >> 3, j = rem2 & 7;
    int k = c * 32 + (l >> 4) * 8 + j;
    int n = t * 16 + (l & 15);
    if (dflag[0]) dst[i] = f2bf(((const float*)src)[k * 96 + n]);
    else          dst[i] = ((const unsigned short*)src)[k * 96 + n];
}

// ---------------------------------------------------------------------------
// MFMA GEMM: out[M,96] = A[M,K] @ W[K,96], v_mfma_f32_16x16x32_bf16.
// Wave owns 16 rows x 96 cols (6 tiles, 6x f32x4 acc). No LDS, no barriers.
// EPI: 0 plain, 1 lrelu(acc+bias), 2 lrelu(acc+bias) -> out and out2
// AWS: 1 if A is workspace bf16, 0 if A is an input (dtype per dflag)
// SD : 1 -> also emit s,d per row from the fp32 acc (fused old sd_k)
// ABN: 1 -> A-load applies BN coef + lrelu + residual inline
// SCAT:1 -> blocks >= ngb instead scatter edges [e0,e1) into the 64-slot CSR
//      (hides the latency-bound atomic scatter under the MFMA-bound GEMM)
// ---------------------------------------------------------------------------
template<int EPI, int AWS, int SD, int ABN, int SCAT>
__global__ __launch_bounds__(256) void mgemm_k(
    const void* __restrict__ Ap, const unsigned short* __restrict__ Wpk,
    const void* __restrict__ bp, const int* __restrict__ dflag,
    unsigned short* __restrict__ out, unsigned short* __restrict__ out2,
    const void* __restrict__ as_, const void* __restrict__ ad_,
    float* __restrict__ s, float* __restrict__ d,
    const float* __restrict__ coefp, const unsigned short* __restrict__ idn,
    const int* __restrict__ ei, int* __restrict__ fill,
    unsigned short* __restrict__ colw, int e0, int e1, int ngb,
    int M, int K)
{
    if (SCAT && (int)blockIdx.x >= ngb) {
        int e = e0 + ((int)blockIdx.x - ngb) * 256 + threadIdx.x;
        if (e < e1) {
            int srcv = ei[e];
            int dstv = ei[N_EDGES + e];
            int p = atomicAdd(&fill[dstv], 1);
            if (p < SLOT) colw[(size_t)dstv * SLOT + p] = (unsigned short)srcv;
        }
        return;
    }

    const int f32  = AWS ? 0 : dflag[0];
    const int wf32 = dflag[0];
    const int l    = threadIdx.x & 63;
    const int wave = threadIdx.x >> 6;
    const int row0 = blockIdx.x * 64 + wave * 16;
    const int m    = l & 15;
    const int q    = l >> 4;
    const int arow = row0 + m;
    const bool aok = arow < M;

    f32x4 acc[6] = {};
    const int nch = K >> 5;
    const bf16x8* wp = (const bf16x8*)Wpk;

    for (int c = 0; c < nch; c++) {
        bf16x8 a = {};
        if (aok) {
            if (ABN) {
                const int f0 = c * 32 + q * 8;
                uint4 xu = *(const uint4*)((const unsigned short*)Ap + (size_t)arow * K + f0);
                uint4 iu = *(const uint4*)(idn + (size_t)arow * K + f0);
                unsigned int xs[4] = { xu.x, xu.y, xu.z, xu.w };
                unsigned int is[4] = { iu.x, iu.y, iu.z, iu.w };
                #pragma unroll
                for (int jj = 0; jj < 4; jj++) {
                    int f = f0 + 2 * jj;
                    float v0 = lrelu01(bf2f(xs[jj] & 0xffff) * coefp[f]     + coefp[96 + f])     + bf2f(is[jj] & 0xffff);
                    float v1 = lrelu01(bf2f(xs[jj] >> 16)    * coefp[f + 1] + coefp[96 + f + 1]) + bf2f(is[jj] >> 16);
                    a[2 * jj]     = (short)f2bf(v0);
                    a[2 * jj + 1] = (short)f2bf(v1);
                }
            } else if (f32) {
                const float* A = (const float*)Ap + (size_t)arow * K + c * 32 + q * 8;
                #pragma unroll
                for (int j = 0; j < 8; j++) a[j] = (short)f2bf(A[j]);
            } else {
                a = *(const bf16x8*)((const unsigned short*)Ap + (size_t)arow * K + c * 32 + q * 8);
            }
        }
        const int base = c * 384 + l;
        #pragma unroll
        for (int t = 0; t < 6; t++)
            acc[t] = __builtin_amdgcn_mfma_f32_16x16x32_bf16(a, wp[base + t * 64], acc[t], 0, 0, 0);
    }

    float bv[6];
    if (EPI > 0) {
        #pragma unroll
        for (int t = 0; t < 6; t++) bv[t] = ldf(bp, t * 16 + m, wf32);
    }
    #pragma unroll
    for (int r = 0; r < 4; r++) {
        int rr = row0 + q * 4 + r;
        if (rr >= M) continue;
        size_t o = (size_t)rr * 96 + m;
        #pragma unroll
        for (int t = 0; t < 6; t++) {
            float v = acc[t][r];
            if (EPI > 0) v = lrelu01(v + bv[t]);
            unsigned short sv = f2bf(v);
            out[o + t * 16] = sv;
            if (EPI == 2) out2[o + t * 16] = sv;
        }
    }

    if (SD) {
        float asv[6], adv[6];
        #pragma unroll
        for (int t = 0; t < 6; t++) {
            asv[t] = ldf(as_, t * 16 + m, wf32);
            adv[t] = ldf(ad_, t * 16 + m, wf32);
        }
        #pragma unroll
        for (int r = 0; r < 4; r++) {
            float ps = 0.f, pd = 0.f;
            #pragma unroll
            for (int t = 0; t < 6; t++) {
                ps = fmaf(acc[t][r], asv[t], ps);
                pd = fmaf(acc[t][r], adv[t], pd);
            }
            #pragma unroll
            for (int off = 1; off < 16; off <<= 1) {
                ps += __shfl_xor(ps, off);
                pd += __shfl_xor(pd, off);
            }
            int rr = row0 + q * 4 + r;
            if (m == 0 && rr < M) { s[rr] = ps; d[rr] = pd; }
        }
    }
}

// ---------------------------------------------------------------------------
// GAT aggregation, one wave per destination node (fixed-stride CSR, real
// edges only — the self-loop is implicit). Softmax via shfl; (u,w) staged in
// per-wave LDS; gather 16-edge-batched over padded deg.
// Block 0 zeroes bnsum; layer 2 blocks also zero the pooled replicas.
// ---------------------------------------------------------------------------
__global__ __launch_bounds__(256) void agg_k(
    const unsigned short* __restrict__ h2, const float* __restrict__ s,
    const float* __restrict__ d, const int* __restrict__ fill,
    const unsigned short* __restrict__ col, const void* __restrict__ bias,
    const int* __restrict__ dflag, unsigned short* __restrict__ out,
    float* __restrict__ bnsum, float* __restrict__ zp, int M)
{
    __shared__ uint2 uwb[4][80];   // 65 entries max + pad (batches reach 80)
    if (blockIdx.x == 0 && threadIdx.x < 192) bnsum[threadIdx.x] = 0.f;
    if (zp) {
        int zi = blockIdx.x * 256 + threadIdx.x;
        if (zi < NREP * REPSZ) zp[zi] = 0.f;
    }
    int f32 = dflag[0];
    int v = (blockIdx.x * blockDim.x + threadIdx.x) >> 6;
    int l = threadIdx.x & 63;
    int wv = threadIdx.x >> 6;
    if (v >= M) return;
    int st   = v * SLOT;
    int degr = min(fill[v], SLOT - 1);   // real edges
    int deg  = degr + 1;                 // + implicit self loop

    float dv = d[v];
    int u = 0; float e = -1e30f;
    if (l < degr) {
        u = col[st + l];
        float t = s[u] + dv;
        e = t >= 0.f ? t : 0.2f * t;
    } else if (l == degr) {
        u = v;
        float t = s[v] + dv;
        e = t >= 0.f ? t : 0.2f * t;
    }
    float lm = e;
    #pragma unroll
    for (int off = 32; off > 0; off >>= 1) lm = fmaxf(lm, __shfl_xor(lm, off));
    float w = (l < deg) ? __expf(e - lm) : 0.f;
    float ls = w;
    #pragma unroll
    for (int off = 32; off > 0; off >>= 1) ls += __shfl_xor(ls, off);
    float rden = 1.0f / ls;

    uwb[wv][l] = make_uint2((unsigned int)u, __float_as_uint(w));
    if (l < 16) uwb[wv][64 + l] = make_uint2(0u, 0u);

    bool hw = (l < 48);
    int  c2 = 2 * l;
    float a0 = 0.f, a1 = 0.f;
    const uint2* myuw = uwb[wv];
    for (int j = 0; j < deg; j += 16) {
        uint2 p[16];
        #pragma unroll
        for (int k = 0; k < 16; k++) p[k] = myuw[j + k];
        if (hw) {
            unsigned int hv[16];
            #pragma unroll
            for (int k = 0; k < 16; k++)
                hv[k] = *(const unsigned int*)(h2 + (size_t)p[k].x * 96 + c2);
            #pragma unroll
            for (int k = 0; k < 16; k++) {
                float wj = __uint_as_float(p[k].y);
                a0 = fmaf(wj, bf2f(hv[k] & 0xffff), a0);
                a1 = fmaf(wj, bf2f(hv[k] >> 16),    a1);
            }
        }
    }
    if (hw) {
        float b0 = ldf(bias, c2,     f32);
        float b1 = ldf(bias, c2 + 1, f32);
        unsigned int o = (unsigned int)f2bf(a0 * rden + b0)
                       | ((unsigned int)f2bf(a1 * rden + b1) << 16);
        *(unsigned int*)(out + (size_t)v * 96 + c2) = o;
    }
}

// ---------------------------------------------------------------------------
// BatchNorm statistics / coefficients
// ---------------------------------------------------------------------------
__global__ __launch_bounds__(192) void bnstats_k(const unsigned short* __restrict__ x,
                                                 float* __restrict__ sums, int M)
{
    int c  = threadIdx.x % 96;
    int g2 = threadIdx.x / 96;
    float s = 0.f, q = 0.f;
    for (int r = blockIdx.x * 2 + g2; r < M; r += gridDim.x * 2) {
        float v = bf2f(x[(size_t)r * 96 + c]);
        s += v; q += v * v;
    }
    __shared__ float lsd[192], lqd[192];
    lsd[threadIdx.x] = s; lqd[threadIdx.x] = q;
    __syncthreads();
    if (g2 == 0) {
        atomicAdd(&sums[c],      s + lsd[threadIdx.x + 96]);
        atomicAdd(&sums[96 + c], q + lqd[threadIdx.x + 96]);
    }
}

__global__ void bncoef_k(const float* __restrict__ sums,
                         const void* __restrict__ g_,
                         const void* __restrict__ b_,
                         const int* __restrict__ dflag,
                         float* __restrict__ coef)
{
    int c = threadIdx.x;
    if (c >= 96) return;
    int f32 = dflag[0];
    float mu  = sums[c] * (1.f / N_NODES);
    float var = sums[96 + c] * (1.f / N_NODES) - mu * mu;
    float rinv = 1.0f / sqrtf(var + BN_EPS);
    float sc = ldf(g_, c, f32) * rinv;
    coef[c]      = sc;
    coef[96 + c] = ldf(b_, c, f32) - mu * sc;
}

// ---------------------------------------------------------------------------
// Fused tail: BN+lrelu+residual -> Poincare expmap0 -> mean-pool, 16
// nodes/wave with full ILP; 8-replica pooled accumulation (blockIdx&7).
// ---------------------------------------------------------------------------
__global__ __launch_bounds__(256) void bnpool_k(
    const unsigned short* __restrict__ h, const float* __restrict__ coef,
    const unsigned short* __restrict__ iden, const int* __restrict__ batch,
    float* __restrict__ pooled8, int M)
{
    int w = (blockIdx.x * blockDim.x + threadIdx.x) >> 6;
    int l = threadIdx.x & 63;
    int v0 = w * 16;
    if (v0 >= M) return;
    float* P = pooled8 + (blockIdx.x & (NREP - 1)) * REPSZ;
    float* C = P + NG * H;
    bool hw = (l < 48);
    int  c2 = 2 * l;
    float sc0 = 0.f, sc1 = 0.f, sh0 = 0.f, sh1 = 0.f;
    if (hw) {
        sc0 = coef[c2]; sc1 = coef[c2 + 1];
        sh0 = coef[96 + c2]; sh1 = coef[97 + c2];
    }
    int nv = min(16, M - v0);

    int gb[16];
    #pragma unroll
    for (int k = 0; k < 16; k++) gb[k] = batch[v0 + min(k, nv - 1)];

    float x0[16], x1[16], q[16];
    #pragma unroll
    for (int k = 0; k < 16; k++) { x0[k] = 0.f; x1[k] = 0.f; q[k] = 0.f; }
    if (hw) {
        unsigned int xu[16], iu[16];
        #pragma unroll
        for (int k = 0; k < 16; k++) {
            int v = v0 + k;
            if (k < nv) {
                xu[k] = *(const unsigned int*)(h    + (size_t)v * 96 + c2);
                iu[k] = *(const unsigned int*)(iden + (size_t)v * 96 + c2);
            } else { xu[k] = 0u; iu[k] = 0u; }
        }
        #pragma unroll
        for (int k = 0; k < 16; k++) {
            x0[k] = lrelu01(bf2f(xu[k] & 0xffff) * sc0 + sh0) + bf2f(iu[k] & 0xffff);
            x1[k] = lrelu01(bf2f(xu[k] >> 16)    * sc1 + sh1) + bf2f(iu[k] >> 16);
            q[k]  = x0[k] * x0[k] + x1[k] * x1[k];
        }
    }

    #pragma unroll
    for (int off = 32; off > 0; off >>= 1) {
        #pragma unroll
        for (int k = 0; k < 16; k++) q[k] += __shfl_xor(q[k], off);
    }

    float f[16];
    #pragma unroll
    for (int k = 0; k < 16; k++) {
        float n = fmaxf(sqrtf(q[k]), 1e-15f);
        if (n < 15.f) {
            float t = __expf(2.f * n);
            f[k] = (t - 1.f) / ((t + 1.f) * n);
        } else {
            f[k] = 1.f / n;
        }
    }

    float a0 = 0.f, a1 = 0.f, cnt = 0.f;
    int curg = -1;
    for (int k = 0; k < nv; k++) {
        int g = gb[k];
        if (g != curg) {
            if (curg >= 0) {
                if (hw) {
                    atomicAdd(&P[curg * 96 + c2],     a0);
                    atomicAdd(&P[curg * 96 + c2 + 1], a1);
                }
                if (l == 0) atomicAdd(&C[curg], cnt);
            }
            a0 = a1 = 0.f; cnt = 0.f; curg = g;
        }
        a0 = fmaf(f[k], x0[k], a0);
        a1 = fmaf(f[k], x1[k], a1);
        cnt += 1.f;
    }
    if (curg >= 0) {
        if (hw) {
            atomicAdd(&P[curg * 96 + c2],     a0);
            atomicAdd(&P[curg * 96 + c2 + 1], a1);
        }
        if (l == 0) atomicAdd(&C[curg], cnt);
    }
}

// ---------------------------------------------------------------------------
// Head: one block per graph. Sums the 8 pooled replicas, then
// pooled/cnt -> fc3+lrelu -> fc4 -> out.
// ---------------------------------------------------------------------------
__global__ __launch_bounds__(64) void head_k(const float* __restrict__ pooled8,
                                             const void* __restrict__ w3,
                                             const void* __restrict__ b3,
                                             const void* __restrict__ w4,
                                             const void* __restrict__ b4,
                                             const int* __restrict__ dflag,
                                             void* __restrict__ outv)
{
    int g = blockIdx.x;
    int t = threadIdx.x;
    int f32 = dflag[0];
    __shared__ float p[96];
    __shared__ float o[48];
    float cs = 0.f;
    #pragma unroll
    for (int r = 0; r < NREP; r++) cs += pooled8[r * REPSZ + NG * H + g];
    float inv = 1.0f / fmaxf(cs, 1.0f);
    for (int c = t; c < 96; c += 64) {
        float v = 0.f;
        #pragma unroll
        for (int r = 0; r < NREP; r++) v += pooled8[r * REPSZ + g * 96 + c];
        p[c] = v * inv;
    }
    __syncthreads();
    if (t < 48) {
        float a = ldf(b3, t, f32);
        #pragma unroll
        for (int c = 0; c < 96; c++) a = fmaf(p[c], ldf(w3, (size_t)c * 48 + t, f32), a);
        o[t] = lrelu01(a);
    }
    __syncthreads();
    if (t < 4) {
        float a = ldf(b4, t, f32);
        #pragma unroll
        for (int j = 0; j < 48; j++) a = fmaf(o[j], ldf(w4, j * 4 + t, f32), a);
        if (f32) ((float*)outv)[g * 4 + t] = a;
        else     ((unsigned short*)outv)[g * 4 + t] = f2bf(a);
    }
}

// ---------------------------------------------------------------------------
extern "C" void kernel_launch(void* const* d_in, const int* in_sizes, int n_in,
                              void* d_out, int out_size, void* d_ws, size_t ws_size,
                              hipStream_t stream)
{
    const void* x     = d_in[0];
    const int*  ei    = (const int*)d_in[1];
    const int*  batch = (const int*)d_in[2];
    const void* embW  = d_in[3];
    const void* embB  = d_in[4];
    const void* convW[3]  = { d_in[5],  d_in[9],  d_in[13] };
    const void* convAs[3] = { d_in[6],  d_in[10], d_in[14] };
    const void* convAd[3] = { d_in[7],  d_in[11], d_in[15] };
    const void* convB[3]  = { d_in[8],  d_in[12], d_in[16] };
    const void* fcW[2]    = { d_in[17], d_in[19] };
    const void* fcB[2]    = { d_in[18], d_in[20] };
    const void* bnG[3]    = { d_in[21], d_in[23], d_in[25] };
    const void* bnB[3]    = { d_in[22], d_in[24], d_in[26] };
    const void* fc3W = d_in[27];
    const void* fc3b = d_in[28];
    const void* fc4W = d_in[29];
    const void* fc4b = d_in[30];

    // ---- workspace layout (~37 MiB of the 256 MiB d_ws) ----
    char* wp_ = (char*)d_ws;
    auto alloc = [&](size_t b) { char* p = wp_; wp_ += (b + 255) & ~(size_t)255; return p; };
    int*   dflag = (int*)alloc(256);
    unsigned short* ident = (unsigned short*)alloc((size_t)N_NODES * H * 2);
    unsigned short* hA    = (unsigned short*)alloc((size_t)N_NODES * H * 2);
    unsigned short* hB    = (unsigned short*)alloc((size_t)N_NODES * H * 2);
    float* s_sc  = (float*)alloc((size_t)N_NODES * 4);
    float* d_sc  = (float*)alloc((size_t)N_NODES * 4);
    float* bnsum = (float*)alloc(192 * 4);
    float* coef  = (float*)alloc(192 * 4);
    float* pooled8 = (float*)alloc((size_t)NREP * REPSZ * 4);
    int*   fill  = (int*)alloc((size_t)N_NODES * 4);
    unsigned short* col = (unsigned short*)alloc((size_t)N_NODES * SLOT * 2);
    // packed MFMA B-fragment weights: emb (256x96) + 5 x (96x96)
    unsigned short* wpkEmb = (unsigned short*)alloc((size_t)F_IN * 96 * 2);
    unsigned short* wpkS[5];
    for (int i = 0; i < 5; i++) wpkS[i] = (unsigned short*)alloc((size_t)H * 96 * 2);

    const int GM = (N_NODES + 63) / 64;          // gemm grid (64 rows/block)
    const int GW = (N_NODES * 64 + 255) / 256;   // wave-per-node grid
    const int GP = ((N_NODES + 15) / 16 * 64 + 255) / 256;  // bnpool grid (16 nodes/wave)
    const int GF = (N_NODES + 255) / 256;        // detect+fill grid
    const int EH = N_EDGES / 2;                  // edge half-point
    const int GS = (EH + 255) / 256;             // scatter blocks per half

    // ---- dtype detect + fill zero (fused) ----
    detect_fill_k<<<GF, 256, 0, stream>>>((const unsigned short*)x, dflag, fill);

    // ---- pack all weights into MFMA fragment order (1 dispatch) ----
    wpackall_k<<<276, 256, 0, stream>>>(embW, convW[0], convW[1], convW[2], fcW[0], fcW[1],
                                        dflag, wpkEmb, wpkS[0], wpkS[1], wpkS[2], wpkS[3], wpkS[4]);

    // ---- embed (+ scatter of edges [0, EH) riding along) ----
    mgemm_k<2, 0, 0, 0, 1><<<GM + GS, 256, 0, stream>>>(
        x, wpkEmb, embB, dflag, hA, ident,
        nullptr, nullptr, nullptr, nullptr, nullptr, nullptr,
        ei, fill, col, 0, EH, GM, N_NODES, F_IN);

    unsigned short* hcur = hA;
    unsigned short* htmp = hB;

    for (int l = 0; l < 3; l++) {
        // h2 = h @ convW, fused s,d; conv0 also carries scatter half 2
        if (l == 0) {
            mgemm_k<0, 1, 1, 0, 1><<<GM + GS, 256, 0, stream>>>(
                hcur, wpkS[0], nullptr, dflag, htmp, nullptr,
                convAs[0], convAd[0], s_sc, d_sc, nullptr, nullptr,
                ei, fill, col, EH, N_EDGES, GM, N_NODES, H);
        } else {
            mgemm_k<0, 1, 1, 0, 0><<<GM, 256, 0, stream>>>(
                hcur, wpkS[l], nullptr, dflag, htmp, nullptr,
                convAs[l], convAd[l], s_sc, d_sc, nullptr, nullptr,
                nullptr, nullptr, nullptr, 0, 0, GM, N_NODES, H);
        }
        // aggregation (zeroes bnsum; layer 2 also zeroes the pooled replicas)
        agg_k<<<GW, 256, 0, stream>>>(htmp, s_sc, d_sc, fill, col, convB[l], dflag, hcur,
                                      bnsum, (l == 2) ? pooled8 : nullptr, N_NODES);
        bnstats_k<<<512, 192, 0, stream>>>(hcur, bnsum, N_NODES);
        bncoef_k<<<1, 128, 0, stream>>>(bnsum, bnG[l], bnB[l], dflag, coef);
        if (l < 2) {
            // fc gemm with BN+lrelu+residual fused into the A-load
            mgemm_k<1, 1, 0, 1, 0><<<GM, 256, 0, stream>>>(
                hcur, wpkS[3 + l], fcB[l], dflag, htmp, nullptr,
                nullptr, nullptr, nullptr, nullptr, coef, ident,
                nullptr, nullptr, nullptr, 0, 0, GM, N_NODES, H);
            unsigned short* t = hcur; hcur = htmp; htmp = t;
        }
    }

    // ---- fused BN+Poincare+pool (8-replica) + head ----
    bnpool_k<<<GP, 256, 0, stream>>>(hcur, coef, ident, batch, pooled8, N_NODES);
    head_k<<<NG, 64, 0, stream>>>(pooled8, fc3W, fc3b, fc4W, fc4b, dflag, d_out);
}